// Round 23
// baseline (469.952 us; speedup 1.0000x reference)
//
#include <hip/hip_runtime.h>
#include <math.h>

#define B    128
#define NLOC 196
#define DV   512
#define EMB  512
#define HD   1024
#define VV   10000
#define TT   20
#define G4   4096   // 4*HD
#define VPAD 10112  // 79*128
#define BH   (B*HD)

typedef short bf16x8 __attribute__((ext_vector_type(8)));
typedef short s16x4  __attribute__((ext_vector_type(4)));
typedef float f32x4  __attribute__((ext_vector_type(4)));

__device__ __forceinline__ unsigned short f2bf(float x) {
    unsigned u = __builtin_bit_cast(unsigned, x);
    unsigned r = (u + 0x7fffu + ((u >> 16) & 1u)) >> 16;
    return (unsigned short)r;
}
__device__ __forceinline__ float bf2f(short s) {
    unsigned u = ((unsigned)(unsigned short)s) << 16;
    return __builtin_bit_cast(float, u);
}

__device__ __forceinline__ void gload_lds16(const void* g, void* lds) {
    __builtin_amdgcn_global_load_lds(
        (const __attribute__((address_space(1))) void*)g,
        (__attribute__((address_space(3))) void*)lds, 16, 0, 0);
}

// ---------------- merged attention: attv dot-products + softmax in one kernel ----------------
__global__ __launch_bounds__(256)
void attn_alpha_kernel(const float* __restrict__ feat, const float* __restrict__ wv,
                       const float* __restrict__ bv, float* __restrict__ alpha) {
    __shared__ float av[256];
    __shared__ float red[256];
    const int b = blockIdx.x;              // B
    const int tid = threadIdx.x, lane = tid & 63, wave = tid >> 6;
    // each wave computes 49 rows: rows wave*49 .. wave*49+48 (4*49 = 196)
    for (int i = 0; i < 49; ++i) {
        int rrow = wave * 49 + i;
        if (rrow < NLOC) {
            const float* p = feat + ((size_t)b * NLOC + rrow) * DV;
            float s = 0.f;
            #pragma unroll
            for (int k = lane; k < DV; k += 64) s += p[k] * wv[k];
            for (int off = 32; off > 0; off >>= 1) s += __shfl_down(s, off);
            if (lane == 0) av[rrow] = s + bv[0];
        }
    }
    __syncthreads();
    float v = (tid < NLOC) ? av[tid] : -1e30f;
    red[tid] = v; __syncthreads();
    for (int s = 128; s > 0; s >>= 1) { if (tid < s) red[tid] = fmaxf(red[tid], red[tid + s]); __syncthreads(); }
    float m = red[0]; __syncthreads();
    float e = (tid < NLOC) ? expf(v - m) : 0.f;
    red[tid] = e; __syncthreads();
    for (int s = 128; s > 0; s >>= 1) { if (tid < s) red[tid] += red[tid + s]; __syncthreads(); }
    float sum = red[0];
    if (tid < NLOC) alpha[b * NLOC + tid] = e / sum;
}

// fused: fmean (mean over n) + ctx (alpha-weighted sum over n) in ONE feature pass
__global__ void fmeanctx_kernel(const float* __restrict__ feat, const float* __restrict__ alpha,
                                short* __restrict__ fmean_b, short* __restrict__ ctx_b) {
    int idx = blockIdx.x * blockDim.x + threadIdx.x;   // B*DV
    if (idx >= B * DV) return;
    int b = idx / DV, d = idx % DV;
    const float* p = feat + (size_t)b * NLOC * DV + d;
    const float* a = alpha + b * NLOC;
    float sm = 0.f, sc = 0.f;
    for (int n = 0; n < NLOC; ++n) {
        float v = p[(size_t)n * DV];
        sm += v;
        sc += a[n] * v;
    }
    fmean_b[idx] = (short)f2bf(sm * (1.0f / NLOC));
    ctx_b[idx]   = (short)f2bf(sc);
}

// vectorized gather: 4 consecutive emb elems per thread
__global__ void emb_gather_kernel(const int* __restrict__ captions, const float* __restrict__ table,
                                  short* __restrict__ emb_b) {
    size_t q = (size_t)blockIdx.x * blockDim.x + threadIdx.x;   // T*B*EMB/4
    if (q >= (size_t)TT * B * EMB / 4) return;
    size_t idx = q * 4;
    int k = (int)(idx % EMB);
    int r = (int)(idx / EMB);      // r = t*B + b
    int t = r / B, b = r % B;
    int cap = captions[b * TT + t];
    float4 v = *(const float4*)&table[(size_t)cap * EMB + k];
    s16x4 o = { (short)f2bf(v.x), (short)f2bf(v.y), (short)f2bf(v.z), (short)f2bf(v.w) };
    *(s16x4*)&emb_b[idx] = o;
}

// ONE merged conversion kernel: ranges [Wout | Wih | Whh(permuted) | Wini_h | Wini_c]
#define N_WOUT ((size_t)VPAD * HD / 4)
#define N_WIH  ((size_t)G4 * HD / 4)
#define N_WHH  ((size_t)G4 * HD / 4)
#define N_WINI ((size_t)HD * DV / 4)
__global__ void convert_all_kernel(const float* __restrict__ W_out, short* __restrict__ Wout_b,
                                   const float* __restrict__ W_ih,  short* __restrict__ Wih_b,
                                   const float* __restrict__ W_hh,  short* __restrict__ Whh_b,
                                   const float* __restrict__ W_ini_h, short* __restrict__ Wini_h_b,
                                   const float* __restrict__ W_ini_c, short* __restrict__ Wini_c_b) {
    size_t q = (size_t)blockIdx.x * blockDim.x + threadIdx.x;
    size_t idx;
    if (q < N_WOUT) {
        idx = q * 4;
        size_t n = (size_t)VV * HD;
        s16x4 o = {0, 0, 0, 0};
        if (idx < n) {
            float4 v = *(const float4*)&W_out[idx];
            o = s16x4{ (short)f2bf(v.x), (short)f2bf(v.y), (short)f2bf(v.z), (short)f2bf(v.w) };
        }
        *(s16x4*)&Wout_b[idx] = o;
        return;
    }
    q -= N_WOUT;
    if (q < N_WIH) {
        idx = q * 4;
        float4 v = *(const float4*)&W_ih[idx];
        s16x4 o = { (short)f2bf(v.x), (short)f2bf(v.y), (short)f2bf(v.z), (short)f2bf(v.w) };
        *(s16x4*)&Wih_b[idx] = o;
        return;
    }
    q -= N_WIH;
    if (q < N_WHH) {
        idx = q * 4;
        int k = (int)(idx & (HD - 1));
        int P = (int)(idx >> 10);
        int u = P >> 2, g = P & 3;
        float4 v = *(const float4*)&W_hh[(size_t)(g * HD + u) * HD + k];
        s16x4 o = { (short)f2bf(v.x), (short)f2bf(v.y), (short)f2bf(v.z), (short)f2bf(v.w) };
        *(s16x4*)&Whh_b[idx] = o;
        return;
    }
    q -= N_WHH;
    if (q < N_WINI) {
        idx = q * 4;
        float4 v = *(const float4*)&W_ini_h[idx];
        s16x4 o = { (short)f2bf(v.x), (short)f2bf(v.y), (short)f2bf(v.z), (short)f2bf(v.w) };
        *(s16x4*)&Wini_h_b[idx] = o;
        return;
    }
    q -= N_WINI;
    if (q < N_WINI) {
        idx = q * 4;
        float4 v = *(const float4*)&W_ini_c[idx];
        s16x4 o = { (short)f2bf(v.x), (short)f2bf(v.y), (short)f2bf(v.z), (short)f2bf(v.w) };
        *(s16x4*)&Wini_c_b[idx] = o;
    }
}

// ---------------- bf16 MFMA GEMM BK=32 (proven) + optional fp32 aux store for col>=1024 ----------------
template<int BN, int WR, int WC, bool BF16OUT>
__global__ __launch_bounds__(256)
void gemm_bf16(const short* __restrict__ A, const short* __restrict__ Bw,
               void* __restrict__ C, float* __restrict__ Caux,
               const float* __restrict__ bias0, const float* __restrict__ bias1,
               int NY, int M, int N, int K, int lda, int ldb, int ldc) {
    constexpr int BM = 128;
    constexpr int BK = 32;
    constexpr int WM = BM / WR;
    constexpr int WN = BN / WC;
    constexpr int FM = WM / 16;
    constexpr int FN = WN / 16;
    __shared__ __align__(16) short As[BM * BK];
    __shared__ __align__(16) short Bs[BN * BK];
    const int tid  = threadIdx.x;
    const int wave = tid >> 6, lane = tid & 63;
    const int wr = wave / WC, wc = wave % WC;

    const int nwg = gridDim.x;
    const int qq = nwg >> 3, rr8 = nwg & 7;
    const int p = blockIdx.x;
    const int xcd = p & 7, slot = p >> 3;
    const int lwg = (xcd < rr8) ? (xcd * (qq + 1) + slot)
                                : (rr8 * (qq + 1) + (xcd - rr8) * qq + slot);
    const int m0 = (lwg % NY) * BM;
    const int n0 = (lwg / NY) * BN;
    const int laneoff = lane * 16;

    f32x4 acc[FM][FN] = {};

    for (int k0 = 0; k0 < K; k0 += BK) {
        #pragma unroll
        for (int r = 0; r < 2; ++r) {
            int o   = r * 4096 + wave * 1024 + laneoff;
            int row = o >> 6;
            int gr  = (o >> 4) & 3;
            int col = ((gr ^ ((row >> 1) & 3)) << 3);
            gload_lds16(A + (size_t)(m0 + row) * lda + k0 + col,
                        (char*)As + r * 4096 + wave * 1024);
        }
        constexpr int BBYTES = BN * BK * 2;
        if constexpr (BBYTES >= 4096) {
            #pragma unroll
            for (int r = 0; r < BBYTES / 4096; ++r) {
                int o   = r * 4096 + wave * 1024 + laneoff;
                int row = o >> 6;
                int gr  = (o >> 4) & 3;
                int col = ((gr ^ ((row >> 1) & 3)) << 3);
                gload_lds16(Bw + (size_t)(n0 + row) * ldb + k0 + col,
                            (char*)Bs + r * 4096 + wave * 1024);
            }
        } else {
            constexpr int NW = BBYTES / 1024;
            if (wave < NW) {
                int o   = wave * 1024 + laneoff;
                int row = o >> 6;
                int gr  = (o >> 4) & 3;
                int col = ((gr ^ ((row >> 1) & 3)) << 3);
                gload_lds16(Bw + (size_t)(n0 + row) * ldb + k0 + col,
                            (char*)Bs + wave * 1024);
            }
        }
        __syncthreads();

        bf16x8 a[FM], b[FN];
        const int kfrg = lane >> 4;
        #pragma unroll
        for (int i = 0; i < FM; ++i) {
            int row = wr * WM + i * 16 + (lane & 15);
            a[i] = *(const bf16x8*)&As[row * BK + ((kfrg ^ ((row >> 1) & 3)) << 3)];
        }
        #pragma unroll
        for (int j = 0; j < FN; ++j) {
            int row = wc * WN + j * 16 + (lane & 15);
            b[j] = *(const bf16x8*)&Bs[row * BK + ((kfrg ^ ((row >> 1) & 3)) << 3)];
        }
        #pragma unroll
        for (int i = 0; i < FM; ++i)
            #pragma unroll
            for (int j = 0; j < FN; ++j)
                acc[i][j] = __builtin_amdgcn_mfma_f32_16x16x32_bf16(a[i], b[j], acc[i][j], 0, 0, 0);
        __syncthreads();
    }

    #pragma unroll
    for (int i = 0; i < FM; ++i) {
        #pragma unroll
        for (int j = 0; j < FN; ++j) {
            int col = n0 + wc * WN + j * 16 + (lane & 15);
            if (col >= N) continue;
            float bv = (bias0 ? bias0[col] : 0.f) + (bias1 ? bias1[col] : 0.f);
            #pragma unroll
            for (int q = 0; q < 4; ++q) {
                int row = m0 + wr * WM + i * 16 + (lane >> 4) * 4 + q;
                if (row < M) {
                    float v = acc[i][j][q] + bv;
                    if constexpr (BF16OUT)
                        ((short*)C)[(size_t)row * ldc + col] = (short)f2bf(v);
                    else
                        ((float*)C)[(size_t)row * ldc + col] = v;
                    if (Caux && col >= 1024)
                        Caux[(size_t)row * 1024 + (col - 1024)] = v;
                }
            }
        }
    }
}

// ---------------- bf16 MFMA GEMM BK=64 (proven) + optional per-(row%128,col) add ----------------
__global__ __launch_bounds__(256)
void gemm_k64(const short* __restrict__ A, const short* __restrict__ Bw,
              short* __restrict__ C,
              const float* __restrict__ bias0, const short* __restrict__ addrow,
              int NY, int M, int N, int K, int lda, int ldb, int ldc) {
    __shared__ __align__(16) short As[128 * 64];   // 16 KB
    __shared__ __align__(16) short Bs[128 * 64];   // 16 KB
    const int tid  = threadIdx.x;
    const int wave = tid >> 6, lane = tid & 63;
    const int wr = wave >> 1, wc = wave & 1;

    const int nwg = gridDim.x;
    const int qq = nwg >> 3, rr8 = nwg & 7;
    const int p = blockIdx.x;
    const int xcd = p & 7, slot = p >> 3;
    const int lwg = (xcd < rr8) ? (xcd * (qq + 1) + slot)
                                : (rr8 * (qq + 1) + (xcd - rr8) * qq + slot);
    const int m0 = (lwg % NY) * 128;
    const int n0 = (lwg / NY) * 128;
    const int laneoff = lane * 16;
    const int kfrg = lane >> 4;

    f32x4 acc[4][4] = {};

    for (int k0 = 0; k0 < K; k0 += 64) {
        #pragma unroll
        for (int r = 0; r < 4; ++r) {
            int o   = r * 4096 + wave * 1024 + laneoff;
            int row = o >> 7;                            // 128 B per row
            int gr  = (o >> 4) & 7;
            int col = ((gr ^ (row & 7)) << 3);
            gload_lds16(A + (size_t)(m0 + row) * lda + k0 + col,
                        (char*)As + r * 4096 + wave * 1024);
            gload_lds16(Bw + (size_t)(n0 + row) * ldb + k0 + col,
                        (char*)Bs + r * 4096 + wave * 1024);
        }
        __syncthreads();

        #pragma unroll
        for (int kh = 0; kh < 2; ++kh) {
            bf16x8 a[4], b[4];
            #pragma unroll
            for (int i = 0; i < 4; ++i) {
                int row = wr * 64 + i * 16 + (lane & 15);
                a[i] = *(const bf16x8*)&As[row * 64 + (((kh * 4 + kfrg) ^ (row & 7)) << 3)];
            }
            #pragma unroll
            for (int j = 0; j < 4; ++j) {
                int row = wc * 64 + j * 16 + (lane & 15);
                b[j] = *(const bf16x8*)&Bs[row * 64 + (((kh * 4 + kfrg) ^ (row & 7)) << 3)];
            }
            #pragma unroll
            for (int i = 0; i < 4; ++i)
                #pragma unroll
                for (int j = 0; j < 4; ++j)
                    acc[i][j] = __builtin_amdgcn_mfma_f32_16x16x32_bf16(a[i], b[j], acc[i][j], 0, 0, 0);
        }
        __syncthreads();
    }

    #pragma unroll
    for (int i = 0; i < 4; ++i) {
        #pragma unroll
        for (int j = 0; j < 4; ++j) {
            int col = n0 + wc * 64 + j * 16 + (lane & 15);
            if (col >= N) continue;
            float bv = bias0 ? bias0[col] : 0.f;
            #pragma unroll
            for (int q = 0; q < 4; ++q) {
                int row = m0 + wr * 64 + i * 16 + (lane >> 4) * 4 + q;
                if (row < M) {
                    float v = acc[i][j][q] + bv;
                    if (addrow) v += bf2f(addrow[(size_t)(row & 127) * ldc + col]);
                    C[(size_t)row * ldc + col] = (short)f2bf(v);
                }
            }
        }
    }
}

// ---------------- fused recurrence step v9c: early gate/c prefetch (T14-lite) ----------------
__global__ __launch_bounds__(256)
void lstm_step9(const short* __restrict__ Hprev, int lda, const short* __restrict__ Whh_p,
                const short* __restrict__ pre_t,
                float* __restrict__ cbuf, short* __restrict__ Hall_t) {
    __shared__ __align__(16) short As[32 * 512];    // 32 KB (half-K)
    __shared__ __align__(16) short Ws[32 * 512];    // 32 KB
    __shared__ float gsm[4][32][8];                 // 4 KB
    const int tid  = threadIdx.x;
    const int lane = tid & 63, wave = tid >> 6;
    const int n0 = blockIdx.x * 32;                 // P base (units blockIdx.x*8..+7)
    const int m0 = blockIdx.y * 32;                 // batch base

    // ---- early prefetch of the elementwise tail's operands (addresses depend
    //      only on blockIdx/tid) -> latency hides under the whole GEMM body ----
    const int m = tid >> 3, u8 = tid & 7;
    const int r = m0 + m, u = blockIdx.x * 8 + u8;
    const size_t pb = (size_t)r * G4 + u;
    const float pre_i = bf2f(pre_t[pb]);
    const float pre_f = bf2f(pre_t[pb + HD]);
    const float pre_g = bf2f(pre_t[pb + 2 * HD]);
    const float pre_o = bf2f(pre_t[pb + 3 * HD]);
    const float c_old = cbuf[(size_t)r * HD + u];

    const int mi = wave >> 1, ni = wave & 1;        // wave's 16x16 tile of the 32x32
    const int arowL = mi * 16 + (lane & 15);
    const int browL = ni * 16 + (lane & 15);
    const int kg    = lane >> 4;

    f32x4 acc = {};

    for (int h2 = 0; h2 < 2; ++h2) {
        const int k0 = h2 * 512;
        #pragma unroll
        for (int it = 0; it < 8; ++it) {
            int fg  = it * 256 + tid;
            int row = fg >> 6;                      // 64 granules (1024 B) per row
            int g   = fg & 63;
            int col = (g ^ (row & 7)) * 8;          // pre-swizzled global elem col
            gload_lds16(Hprev + (size_t)(m0 + row) * lda + k0 + col,
                        (char*)As + it * 4096 + wave * 1024);
            gload_lds16(Whh_p + (size_t)(n0 + row) * HD + k0 + col,
                        (char*)Ws + it * 4096 + wave * 1024);
        }
        __syncthreads();
        #pragma unroll
        for (int ks = 0; ks < 16; ++ks) {
            int lg = ks * 4 + kg;                   // logical granule 0..63
            bf16x8 a = *(const bf16x8*)((const char*)As + arowL * 1024 + ((lg ^ (arowL & 7)) << 4));
            bf16x8 w = *(const bf16x8*)((const char*)Ws + browL * 1024 + ((lg ^ (browL & 7)) << 4));
            acc = __builtin_amdgcn_mfma_f32_16x16x32_bf16(a, w, acc, 0, 0, 0);
        }
        __syncthreads();                            // reads done before restage
    }

    // scatter gates: wave tile (mi, ni); lane col p = browL -> unit p>>2, gate p&3
    #pragma unroll
    for (int q = 0; q < 4; ++q) {
        int rr = mi * 16 + (lane >> 4) * 4 + q;
        gsm[browL & 3][rr][browL >> 2] = acc[q];
    }
    __syncthreads();

    // fused LSTM elementwise: operands prefetched at kernel entry
    float gi  = gsm[0][m][u8] + pre_i;
    float gf  = gsm[1][m][u8] + pre_f;
    float gg2 = gsm[2][m][u8] + pre_g;
    float go  = gsm[3][m][u8] + pre_o;
    float si = 1.f / (1.f + expf(-gi));
    float sf = 1.f / (1.f + expf(-gf));
    float so = 1.f / (1.f + expf(-go));
    float cn = sf * c_old + si * tanhf(gg2);
    float hn = so * tanhf(cn);
    cbuf[(size_t)r * HD + u] = cn;
    Hall_t[(size_t)r * HD + u] = (short)f2bf(hn);
}

// ---------------- single-pass LDS softmax: bf16 logits in, two fp32 outputs ----------------
__global__ __launch_bounds__(512)
void softmax_kernel(const short* __restrict__ wbf, float* __restrict__ logout,
                    float* __restrict__ smout) {
    __shared__ float rowbuf[VV];   // 40 KB
    __shared__ float red[512];
    int r = blockIdx.x;            // T*B rows
    int tid = threadIdx.x;         // 512
    const short* row = wbf + (size_t)r * VV;
    float m = -1e30f;
    for (int i = tid; i < VV; i += 512) {
        float v = bf2f(row[i]);
        rowbuf[i] = v;
        m = fmaxf(m, v);
    }
    red[tid] = m; __syncthreads();
    for (int s = 256; s > 0; s >>= 1) { if (tid < s) red[tid] = fmaxf(red[tid], red[tid + s]); __syncthreads(); }
    m = red[0]; __syncthreads();
    float sum = 0.f;
    for (int i = tid; i < VV; i += 512) sum += expf(rowbuf[i] - m);
    red[tid] = sum; __syncthreads();
    for (int s = 256; s > 0; s >>= 1) { if (tid < s) red[tid] += red[tid + s]; __syncthreads(); }
    sum = red[0];
    float inv = 1.f / sum;
    float lz = logf(sum);
    for (int i = tid; i < VV; i += 512) {
        float x = rowbuf[i];
        smout[(size_t)r * VV + i]  = expf(x - m) * inv;
        logout[(size_t)r * VV + i] = x - m - lz;
    }
}

// ---------------- launch ----------------
extern "C" void kernel_launch(void* const* d_in, const int* in_sizes, int n_in,
                              void* d_out, int out_size, void* d_ws, size_t ws_size,
                              hipStream_t stream) {
    const float* features    = (const float*)d_in[0];
    const int*   captions    = (const int*)  d_in[1];
    const float* W_init_h    = (const float*)d_in[2];
    const float* W_init_c    = (const float*)d_in[3];
    const float* W_attn_v    = (const float*)d_in[4];
    const float* b_attn_v    = (const float*)d_in[5];
    // d_in[6], d_in[7] (W_attn_h, b_attn_h) dead: softmax shift-invariance.
    const float* embed_table = (const float*)d_in[8];
    const float* W_ih        = (const float*)d_in[9];
    const float* W_hh        = (const float*)d_in[10];
    const float* b_ih        = (const float*)d_in[11];
    const float* b_hh        = (const float*)d_in[12];
    const float* W_out       = (const float*)d_in[13];
    const float* b_out       = (const float*)d_in[14];

    float* out   = (float*)d_out;
    float* words = out;                        // first half: final log_softmax
    float* s2    = out + (size_t)TT * B * VV;  // second half: scratch, then softmax out

    // second-half scratch — slot offsets FROZEN
    short* gate_pre_b = (short*)s2;                              // bf16 in frozen slot
    short* Hall_b   = (short*)(s2 + (size_t)10485760);           // TT x B*HD bf16
    short* Wout_b   = (short*)(s2 + (size_t)10485760 + 1310720); // VPAD*HD
    short* Wih_b    = Wout_b + (size_t)VPAD * HD;
    short* Whh_b    = Wih_b  + (size_t)G4 * HD;                  // PERMUTED W_hh
    short* Wini_h_b = Whh_b  + (size_t)G4 * HD;                  // [1024][512]
    short* Wini_c_b = Wini_h_b + (size_t)HD * DV;                // [1024][512] (contiguous)

    // ws small scratch (+ bf16 words buffer)
    char* w = (char*)d_ws;
    size_t off = 0;
    auto alloc = [&](size_t bytes) { void* p = w + off; off = (off + bytes + 255) & ~255UL; return p; };
    float* alpha  = (float*)alloc((size_t)B * NLOC * 4);
    short* gctx_b = (short*)alloc((size_t)B * G4 * 2);
    float* cbuf   = (float*)alloc((size_t)B * HD * 4);
    short* fmean_b= (short*)alloc((size_t)B * DV * 2);
    short* ctx_b  = (short*)alloc((size_t)B * DV * 2);
    short* hc_b   = (short*)alloc((size_t)B * 2048 * 2);         // [128][2048]: h0 | c0
    short* emb_b  = (short*)alloc((size_t)TT * B * EMB * 2);
    short* words_bf = (short*)alloc((size_t)TT * B * VV * 2);    // 51.2 MB

    // ---- merged weight conversion (one launch) ----
    {
        size_t total = N_WOUT + N_WIH + N_WHH + 2 * N_WINI;
        convert_all_kernel<<<(total + 255) / 256, 256, 0, stream>>>(
            W_out, Wout_b, W_ih, Wih_b, W_hh, Whh_b,
            W_init_h, Wini_h_b, W_init_c, Wini_c_b);
    }

    // ---- phase 1: time-parallel (attv+alpha merged) ----
    attn_alpha_kernel<<<B, 256, 0, stream>>>(features, W_attn_v, b_attn_v, alpha);
    fmeanctx_kernel<<<(B * DV + 255) / 256, 256, 0, stream>>>(features, alpha, fmean_b, ctx_b);
    emb_gather_kernel<<<((size_t)TT * B * EMB / 4 + 255) / 256, 256, 0, stream>>>(
        captions, embed_table, emb_b);

    // fused h0|c0 GEMM: [128][2048] = fmean @ [Wini_h; Wini_c]^T; c-half also
    // stored fp32 straight into cbuf via the Caux epilogue
    gemm_bf16<32, 4, 1, true><<<dim3(2048 / 32), 256, 0, stream>>>(
        fmean_b, Wini_h_b, hc_b, cbuf, nullptr, nullptr, 1, B, 2048, DV, DV, DV, 2048);

    // gctx (bf16 out, BK=32 proven)
    gemm_bf16<32, 4, 1, true><<<dim3(G4 / 32), 256, 0, stream>>>(
        ctx_b, Wih_b, gctx_b, nullptr, b_ih, b_hh, 1, B, G4, DV, DV, HD, G4);
    // gate_pre (bf16 out, BK=64, XCD swizzle; gctx folded in via addrow epilogue)
    gemm_k64<<<dim3((G4 / 128) * (TT * B / 128)), 256, 0, stream>>>(
        emb_b, Wih_b + DV, gate_pre_b, nullptr, gctx_b, TT * B / 128,
        TT * B, G4, EMB, EMB, DV + EMB, G4);

    // ---- phase 2: fused recurrence (v9c: early prefetch) ----
    for (int t = 0; t < TT; ++t) {
        const short* Hprev = (t == 0) ? hc_b : (Hall_b + (size_t)(t - 1) * BH);
        int lda = (t == 0) ? 2048 : HD;
        lstm_step9<<<dim3(G4 / 32, B / 32), 256, 0, stream>>>(
            Hprev, lda, Whh_b, gate_pre_b + (size_t)t * B * G4,
            cbuf, Hall_b + (size_t)t * BH);
    }

    // ---- phase 3: words (bf16) = Hall @ W_out^T + b_out (BK=64, XCD swizzle) ----
    gemm_k64<<<dim3((VPAD / 128) * (TT * B / 128)), 256, 0, stream>>>(
        Hall_b, Wout_b, words_bf, b_out, nullptr, TT * B / 128,
        TT * B, VV, HD, HD, HD, VV);
    softmax_kernel<<<TT * B, 512, 0, stream>>>(words_bf, words, s2);
}

// Round 24
// 430.063 us; speedup vs baseline: 1.0928x; 1.0928x over previous
//
#include <hip/hip_runtime.h>
#include <math.h>

#define B    128
#define NLOC 196
#define DV   512
#define EMB  512
#define HD   1024
#define VV   10000
#define TT   20
#define G4   4096   // 4*HD
#define VPAD 10112  // 79*128
#define BH   (B*HD)

typedef short bf16x8 __attribute__((ext_vector_type(8)));
typedef short s16x4  __attribute__((ext_vector_type(4)));
typedef float f32x4  __attribute__((ext_vector_type(4)));

__device__ __forceinline__ unsigned short f2bf(float x) {
    unsigned u = __builtin_bit_cast(unsigned, x);
    unsigned r = (u + 0x7fffu + ((u >> 16) & 1u)) >> 16;
    return (unsigned short)r;
}
__device__ __forceinline__ float bf2f(short s) {
    unsigned u = ((unsigned)(unsigned short)s) << 16;
    return __builtin_bit_cast(float, u);
}

__device__ __forceinline__ void gload_lds16(const void* g, void* lds) {
    __builtin_amdgcn_global_load_lds(
        (const __attribute__((address_space(1))) void*)g,
        (__attribute__((address_space(3))) void*)lds, 16, 0, 0);
}

// ---------------- small kernels ----------------

__global__ void attv_kernel(const float* __restrict__ feat, const float* __restrict__ wv,
                            const float* __restrict__ bv, float* __restrict__ attv) {
    int row  = blockIdx.x;         // B*NLOC
    int lane = threadIdx.x;        // 64
    const float* p = feat + (size_t)row * DV;
    float s = 0.f;
    for (int k = lane; k < DV; k += 64) s += p[k] * wv[k];
    for (int off = 32; off > 0; off >>= 1) s += __shfl_down(s, off);
    if (lane == 0) attv[row] = s + bv[0];
}

__global__ void alpha_kernel(const float* __restrict__ attv, float* __restrict__ alpha) {
    int b   = blockIdx.x;          // B
    int tid = threadIdx.x;         // 256
    __shared__ float red[256];
    float v = (tid < NLOC) ? attv[b * NLOC + tid] : -1e30f;
    red[tid] = v; __syncthreads();
    for (int s = 128; s > 0; s >>= 1) { if (tid < s) red[tid] = fmaxf(red[tid], red[tid + s]); __syncthreads(); }
    float m = red[0]; __syncthreads();
    float e = (tid < NLOC) ? expf(v - m) : 0.f;
    red[tid] = e; __syncthreads();
    for (int s = 128; s > 0; s >>= 1) { if (tid < s) red[tid] += red[tid + s]; __syncthreads(); }
    float sum = red[0];
    if (tid < NLOC) alpha[b * NLOC + tid] = e / sum;
}

// fused: fmean (mean over n) + ctx (alpha-weighted sum over n) in ONE feature pass
__global__ void fmeanctx_kernel(const float* __restrict__ feat, const float* __restrict__ alpha,
                                short* __restrict__ fmean_b, short* __restrict__ ctx_b) {
    int idx = blockIdx.x * blockDim.x + threadIdx.x;   // B*DV
    if (idx >= B * DV) return;
    int b = idx / DV, d = idx % DV;
    const float* p = feat + (size_t)b * NLOC * DV + d;
    const float* a = alpha + b * NLOC;
    float sm = 0.f, sc = 0.f;
    for (int n = 0; n < NLOC; ++n) {
        float v = p[(size_t)n * DV];
        sm += v;
        sc += a[n] * v;
    }
    fmean_b[idx] = (short)f2bf(sm * (1.0f / NLOC));
    ctx_b[idx]   = (short)f2bf(sc);
}

// vectorized gather: 4 consecutive emb elems per thread
__global__ void emb_gather_kernel(const int* __restrict__ captions, const float* __restrict__ table,
                                  short* __restrict__ emb_b) {
    size_t q = (size_t)blockIdx.x * blockDim.x + threadIdx.x;   // T*B*EMB/4
    if (q >= (size_t)TT * B * EMB / 4) return;
    size_t idx = q * 4;
    int k = (int)(idx % EMB);
    int r = (int)(idx / EMB);      // r = t*B + b
    int t = r / B, b = r % B;
    int cap = captions[b * TT + t];
    float4 v = *(const float4*)&table[(size_t)cap * EMB + k];
    s16x4 o = { (short)f2bf(v.x), (short)f2bf(v.y), (short)f2bf(v.z), (short)f2bf(v.w) };
    *(s16x4*)&emb_b[idx] = o;
}

// ONE merged conversion kernel: ranges [Wout | Wih | Whh(permuted) | Wini_h | Wini_c]
#define N_WOUT ((size_t)VPAD * HD / 4)
#define N_WIH  ((size_t)G4 * HD / 4)
#define N_WHH  ((size_t)G4 * HD / 4)
#define N_WINI ((size_t)HD * DV / 4)
__global__ void convert_all_kernel(const float* __restrict__ W_out, short* __restrict__ Wout_b,
                                   const float* __restrict__ W_ih,  short* __restrict__ Wih_b,
                                   const float* __restrict__ W_hh,  short* __restrict__ Whh_b,
                                   const float* __restrict__ W_ini_h, short* __restrict__ Wini_h_b,
                                   const float* __restrict__ W_ini_c, short* __restrict__ Wini_c_b) {
    size_t q = (size_t)blockIdx.x * blockDim.x + threadIdx.x;
    size_t idx;
    if (q < N_WOUT) {
        idx = q * 4;
        size_t n = (size_t)VV * HD;
        s16x4 o = {0, 0, 0, 0};
        if (idx < n) {
            float4 v = *(const float4*)&W_out[idx];
            o = s16x4{ (short)f2bf(v.x), (short)f2bf(v.y), (short)f2bf(v.z), (short)f2bf(v.w) };
        }
        *(s16x4*)&Wout_b[idx] = o;
        return;
    }
    q -= N_WOUT;
    if (q < N_WIH) {
        idx = q * 4;
        float4 v = *(const float4*)&W_ih[idx];
        s16x4 o = { (short)f2bf(v.x), (short)f2bf(v.y), (short)f2bf(v.z), (short)f2bf(v.w) };
        *(s16x4*)&Wih_b[idx] = o;
        return;
    }
    q -= N_WIH;
    if (q < N_WHH) {
        idx = q * 4;
        int k = (int)(idx & (HD - 1));
        int P = (int)(idx >> 10);
        int u = P >> 2, g = P & 3;
        float4 v = *(const float4*)&W_hh[(size_t)(g * HD + u) * HD + k];
        s16x4 o = { (short)f2bf(v.x), (short)f2bf(v.y), (short)f2bf(v.z), (short)f2bf(v.w) };
        *(s16x4*)&Whh_b[idx] = o;
        return;
    }
    q -= N_WHH;
    if (q < N_WINI) {
        idx = q * 4;
        float4 v = *(const float4*)&W_ini_h[idx];
        s16x4 o = { (short)f2bf(v.x), (short)f2bf(v.y), (short)f2bf(v.z), (short)f2bf(v.w) };
        *(s16x4*)&Wini_h_b[idx] = o;
        return;
    }
    q -= N_WINI;
    if (q < N_WINI) {
        idx = q * 4;
        float4 v = *(const float4*)&W_ini_c[idx];
        s16x4 o = { (short)f2bf(v.x), (short)f2bf(v.y), (short)f2bf(v.z), (short)f2bf(v.w) };
        *(s16x4*)&Wini_c_b[idx] = o;
    }
}

// ---------------- bf16 MFMA GEMM BK=32 (proven) + optional fp32 aux store for col>=1024 ----------------
template<int BN, int WR, int WC, bool BF16OUT>
__global__ __launch_bounds__(256)
void gemm_bf16(const short* __restrict__ A, const short* __restrict__ Bw,
               void* __restrict__ C, float* __restrict__ Caux,
               const float* __restrict__ bias0, const float* __restrict__ bias1,
               int NY, int M, int N, int K, int lda, int ldb, int ldc) {
    constexpr int BM = 128;
    constexpr int BK = 32;
    constexpr int WM = BM / WR;
    constexpr int WN = BN / WC;
    constexpr int FM = WM / 16;
    constexpr int FN = WN / 16;
    __shared__ __align__(16) short As[BM * BK];
    __shared__ __align__(16) short Bs[BN * BK];
    const int tid  = threadIdx.x;
    const int wave = tid >> 6, lane = tid & 63;
    const int wr = wave / WC, wc = wave % WC;

    const int nwg = gridDim.x;
    const int qq = nwg >> 3, rr8 = nwg & 7;
    const int p = blockIdx.x;
    const int xcd = p & 7, slot = p >> 3;
    const int lwg = (xcd < rr8) ? (xcd * (qq + 1) + slot)
                                : (rr8 * (qq + 1) + (xcd - rr8) * qq + slot);
    const int m0 = (lwg % NY) * BM;
    const int n0 = (lwg / NY) * BN;
    const int laneoff = lane * 16;

    f32x4 acc[FM][FN] = {};

    for (int k0 = 0; k0 < K; k0 += BK) {
        #pragma unroll
        for (int r = 0; r < 2; ++r) {
            int o   = r * 4096 + wave * 1024 + laneoff;
            int row = o >> 6;
            int gr  = (o >> 4) & 3;
            int col = ((gr ^ ((row >> 1) & 3)) << 3);
            gload_lds16(A + (size_t)(m0 + row) * lda + k0 + col,
                        (char*)As + r * 4096 + wave * 1024);
        }
        constexpr int BBYTES = BN * BK * 2;
        if constexpr (BBYTES >= 4096) {
            #pragma unroll
            for (int r = 0; r < BBYTES / 4096; ++r) {
                int o   = r * 4096 + wave * 1024 + laneoff;
                int row = o >> 6;
                int gr  = (o >> 4) & 3;
                int col = ((gr ^ ((row >> 1) & 3)) << 3);
                gload_lds16(Bw + (size_t)(n0 + row) * ldb + k0 + col,
                            (char*)Bs + r * 4096 + wave * 1024);
            }
        } else {
            constexpr int NW = BBYTES / 1024;
            if (wave < NW) {
                int o   = wave * 1024 + laneoff;
                int row = o >> 6;
                int gr  = (o >> 4) & 3;
                int col = ((gr ^ ((row >> 1) & 3)) << 3);
                gload_lds16(Bw + (size_t)(n0 + row) * ldb + k0 + col,
                            (char*)Bs + wave * 1024);
            }
        }
        __syncthreads();

        bf16x8 a[FM], b[FN];
        const int kfrg = lane >> 4;
        #pragma unroll
        for (int i = 0; i < FM; ++i) {
            int row = wr * WM + i * 16 + (lane & 15);
            a[i] = *(const bf16x8*)&As[row * BK + ((kfrg ^ ((row >> 1) & 3)) << 3)];
        }
        #pragma unroll
        for (int j = 0; j < FN; ++j) {
            int row = wc * WN + j * 16 + (lane & 15);
            b[j] = *(const bf16x8*)&Bs[row * BK + ((kfrg ^ ((row >> 1) & 3)) << 3)];
        }
        #pragma unroll
        for (int i = 0; i < FM; ++i)
            #pragma unroll
            for (int j = 0; j < FN; ++j)
                acc[i][j] = __builtin_amdgcn_mfma_f32_16x16x32_bf16(a[i], b[j], acc[i][j], 0, 0, 0);
        __syncthreads();
    }

    #pragma unroll
    for (int i = 0; i < FM; ++i) {
        #pragma unroll
        for (int j = 0; j < FN; ++j) {
            int col = n0 + wc * WN + j * 16 + (lane & 15);
            if (col >= N) continue;
            float bv = (bias0 ? bias0[col] : 0.f) + (bias1 ? bias1[col] : 0.f);
            #pragma unroll
            for (int q = 0; q < 4; ++q) {
                int row = m0 + wr * WM + i * 16 + (lane >> 4) * 4 + q;
                if (row < M) {
                    float v = acc[i][j][q] + bv;
                    if constexpr (BF16OUT)
                        ((short*)C)[(size_t)row * ldc + col] = (short)f2bf(v);
                    else
                        ((float*)C)[(size_t)row * ldc + col] = v;
                    if (Caux && col >= 1024)
                        Caux[(size_t)row * 1024 + (col - 1024)] = v;
                }
            }
        }
    }
}

// ---------------- bf16 MFMA GEMM BK=64 (proven) + optional per-(row%128,col) add ----------------
__global__ __launch_bounds__(256)
void gemm_k64(const short* __restrict__ A, const short* __restrict__ Bw,
              short* __restrict__ C,
              const float* __restrict__ bias0, const short* __restrict__ addrow,
              int NY, int M, int N, int K, int lda, int ldb, int ldc) {
    __shared__ __align__(16) short As[128 * 64];   // 16 KB
    __shared__ __align__(16) short Bs[128 * 64];   // 16 KB
    const int tid  = threadIdx.x;
    const int wave = tid >> 6, lane = tid & 63;
    const int wr = wave >> 1, wc = wave & 1;

    const int nwg = gridDim.x;
    const int qq = nwg >> 3, rr8 = nwg & 7;
    const int p = blockIdx.x;
    const int xcd = p & 7, slot = p >> 3;
    const int lwg = (xcd < rr8) ? (xcd * (qq + 1) + slot)
                                : (rr8 * (qq + 1) + (xcd - rr8) * qq + slot);
    const int m0 = (lwg % NY) * 128;
    const int n0 = (lwg / NY) * 128;
    const int laneoff = lane * 16;
    const int kfrg = lane >> 4;

    f32x4 acc[4][4] = {};

    for (int k0 = 0; k0 < K; k0 += 64) {
        #pragma unroll
        for (int r = 0; r < 4; ++r) {
            int o   = r * 4096 + wave * 1024 + laneoff;
            int row = o >> 7;                            // 128 B per row
            int gr  = (o >> 4) & 7;
            int col = ((gr ^ (row & 7)) << 3);
            gload_lds16(A + (size_t)(m0 + row) * lda + k0 + col,
                        (char*)As + r * 4096 + wave * 1024);
            gload_lds16(Bw + (size_t)(n0 + row) * ldb + k0 + col,
                        (char*)Bs + r * 4096 + wave * 1024);
        }
        __syncthreads();

        #pragma unroll
        for (int kh = 0; kh < 2; ++kh) {
            bf16x8 a[4], b[4];
            #pragma unroll
            for (int i = 0; i < 4; ++i) {
                int row = wr * 64 + i * 16 + (lane & 15);
                a[i] = *(const bf16x8*)&As[row * 64 + (((kh * 4 + kfrg) ^ (row & 7)) << 3)];
            }
            #pragma unroll
            for (int j = 0; j < 4; ++j) {
                int row = wc * 64 + j * 16 + (lane & 15);
                b[j] = *(const bf16x8*)&Bs[row * 64 + (((kh * 4 + kfrg) ^ (row & 7)) << 3)];
            }
            #pragma unroll
            for (int i = 0; i < 4; ++i)
                #pragma unroll
                for (int j = 0; j < 4; ++j)
                    acc[i][j] = __builtin_amdgcn_mfma_f32_16x16x32_bf16(a[i], b[j], acc[i][j], 0, 0, 0);
        }
        __syncthreads();
    }

    #pragma unroll
    for (int i = 0; i < 4; ++i) {
        #pragma unroll
        for (int j = 0; j < 4; ++j) {
            int col = n0 + wc * 64 + j * 16 + (lane & 15);
            if (col >= N) continue;
            float bv = bias0 ? bias0[col] : 0.f;
            #pragma unroll
            for (int q = 0; q < 4; ++q) {
                int row = m0 + wr * 64 + i * 16 + (lane >> 4) * 4 + q;
                if (row < M) {
                    float v = acc[i][j][q] + bv;
                    if (addrow) v += bf2f(addrow[(size_t)(row & 127) * ldc + col]);
                    C[(size_t)row * ldc + col] = (short)f2bf(v);
                }
            }
        }
    }
}

// ---------------- fused recurrence step v9b (round-20/22 proven): gctx pre-folded ----------------
__global__ __launch_bounds__(256)
void lstm_step9(const short* __restrict__ Hprev, int lda, const short* __restrict__ Whh_p,
                const short* __restrict__ pre_t,
                float* __restrict__ cbuf, short* __restrict__ Hall_t) {
    __shared__ __align__(16) short As[32 * 512];    // 32 KB (half-K)
    __shared__ __align__(16) short Ws[32 * 512];    // 32 KB
    __shared__ float gsm[4][32][8];                 // 4 KB
    const int tid  = threadIdx.x;
    const int lane = tid & 63, wave = tid >> 6;
    const int n0 = blockIdx.x * 32;                 // P base (units blockIdx.x*8..+7)
    const int m0 = blockIdx.y * 32;                 // batch base

    const int mi = wave >> 1, ni = wave & 1;        // wave's 16x16 tile of the 32x32
    const int arowL = mi * 16 + (lane & 15);
    const int browL = ni * 16 + (lane & 15);
    const int kg    = lane >> 4;

    f32x4 acc = {};

    for (int h2 = 0; h2 < 2; ++h2) {
        const int k0 = h2 * 512;
        #pragma unroll
        for (int it = 0; it < 8; ++it) {
            int fg  = it * 256 + tid;
            int row = fg >> 6;                      // 64 granules (1024 B) per row
            int g   = fg & 63;
            int col = (g ^ (row & 7)) * 8;          // pre-swizzled global elem col
            gload_lds16(Hprev + (size_t)(m0 + row) * lda + k0 + col,
                        (char*)As + it * 4096 + wave * 1024);
            gload_lds16(Whh_p + (size_t)(n0 + row) * HD + k0 + col,
                        (char*)Ws + it * 4096 + wave * 1024);
        }
        __syncthreads();
        #pragma unroll
        for (int ks = 0; ks < 16; ++ks) {
            int lg = ks * 4 + kg;                   // logical granule 0..63
            bf16x8 a = *(const bf16x8*)((const char*)As + arowL * 1024 + ((lg ^ (arowL & 7)) << 4));
            bf16x8 w = *(const bf16x8*)((const char*)Ws + browL * 1024 + ((lg ^ (browL & 7)) << 4));
            acc = __builtin_amdgcn_mfma_f32_16x16x32_bf16(a, w, acc, 0, 0, 0);
        }
        __syncthreads();                            // reads done before restage
    }

    // scatter gates: wave tile (mi, ni); lane col p = browL -> unit p>>2, gate p&3
    #pragma unroll
    for (int q = 0; q < 4; ++q) {
        int rr = mi * 16 + (lane >> 4) * 4 + q;
        gsm[browL & 3][rr][browL >> 2] = acc[q];
    }
    __syncthreads();

    // fused LSTM elementwise: pre_t already contains gctx + biases
    const int m = tid >> 3, u8 = tid & 7;
    const int r = m0 + m, u = blockIdx.x * 8 + u8;
    size_t pb = (size_t)r * G4 + u;
    float gi  = gsm[0][m][u8] + bf2f(pre_t[pb]);
    float gf  = gsm[1][m][u8] + bf2f(pre_t[pb + HD]);
    float gg2 = gsm[2][m][u8] + bf2f(pre_t[pb + 2 * HD]);
    float go  = gsm[3][m][u8] + bf2f(pre_t[pb + 3 * HD]);
    float si = 1.f / (1.f + expf(-gi));
    float sf = 1.f / (1.f + expf(-gf));
    float so = 1.f / (1.f + expf(-go));
    float cn = sf * cbuf[(size_t)r * HD + u] + si * tanhf(gg2);
    float hn = so * tanhf(cn);
    cbuf[(size_t)r * HD + u] = cn;
    Hall_t[(size_t)r * HD + u] = (short)f2bf(hn);
}

// ---------------- single-pass LDS softmax: bf16 logits in, two fp32 outputs ----------------
__global__ __launch_bounds__(512)
void softmax_kernel(const short* __restrict__ wbf, float* __restrict__ logout,
                    float* __restrict__ smout) {
    __shared__ float rowbuf[VV];   // 40 KB
    __shared__ float red[512];
    int r = blockIdx.x;            // T*B rows
    int tid = threadIdx.x;         // 512
    const short* row = wbf + (size_t)r * VV;
    float m = -1e30f;
    for (int i = tid; i < VV; i += 512) {
        float v = bf2f(row[i]);
        rowbuf[i] = v;
        m = fmaxf(m, v);
    }
    red[tid] = m; __syncthreads();
    for (int s = 256; s > 0; s >>= 1) { if (tid < s) red[tid] = fmaxf(red[tid], red[tid + s]); __syncthreads(); }
    m = red[0]; __syncthreads();
    float sum = 0.f;
    for (int i = tid; i < VV; i += 512) sum += expf(rowbuf[i] - m);
    red[tid] = sum; __syncthreads();
    for (int s = 256; s > 0; s >>= 1) { if (tid < s) red[tid] += red[tid + s]; __syncthreads(); }
    sum = red[0];
    float inv = 1.f / sum;
    float lz = logf(sum);
    for (int i = tid; i < VV; i += 512) {
        float x = rowbuf[i];
        smout[(size_t)r * VV + i]  = expf(x - m) * inv;
        logout[(size_t)r * VV + i] = x - m - lz;
    }
}

// ---------------- launch ----------------
extern "C" void kernel_launch(void* const* d_in, const int* in_sizes, int n_in,
                              void* d_out, int out_size, void* d_ws, size_t ws_size,
                              hipStream_t stream) {
    const float* features    = (const float*)d_in[0];
    const int*   captions    = (const int*)  d_in[1];
    const float* W_init_h    = (const float*)d_in[2];
    const float* W_init_c    = (const float*)d_in[3];
    const float* W_attn_v    = (const float*)d_in[4];
    const float* b_attn_v    = (const float*)d_in[5];
    // d_in[6], d_in[7] (W_attn_h, b_attn_h) dead: softmax shift-invariance.
    const float* embed_table = (const float*)d_in[8];
    const float* W_ih        = (const float*)d_in[9];
    const float* W_hh        = (const float*)d_in[10];
    const float* b_ih        = (const float*)d_in[11];
    const float* b_hh        = (const float*)d_in[12];
    const float* W_out       = (const float*)d_in[13];
    const float* b_out       = (const float*)d_in[14];

    float* out   = (float*)d_out;
    float* words = out;                        // first half: final log_softmax
    float* s2    = out + (size_t)TT * B * VV;  // second half: scratch, then softmax out

    // second-half scratch — slot offsets FROZEN
    short* gate_pre_b = (short*)s2;                              // bf16 in frozen slot
    short* Hall_b   = (short*)(s2 + (size_t)10485760);           // TT x B*HD bf16
    short* Wout_b   = (short*)(s2 + (size_t)10485760 + 1310720); // VPAD*HD
    short* Wih_b    = Wout_b + (size_t)VPAD * HD;
    short* Whh_b    = Wih_b  + (size_t)G4 * HD;                  // PERMUTED W_hh
    short* Wini_h_b = Whh_b  + (size_t)G4 * HD;                  // [1024][512]
    short* Wini_c_b = Wini_h_b + (size_t)HD * DV;                // [1024][512] (contiguous)

    // ws small scratch (+ bf16 words buffer)
    char* w = (char*)d_ws;
    size_t off = 0;
    auto alloc = [&](size_t bytes) { void* p = w + off; off = (off + bytes + 255) & ~255UL; return p; };
    float* attv   = (float*)alloc((size_t)B * NLOC * 4);
    float* alpha  = (float*)alloc((size_t)B * NLOC * 4);
    short* gctx_b = (short*)alloc((size_t)B * G4 * 2);
    float* cbuf   = (float*)alloc((size_t)B * HD * 4);
    short* fmean_b= (short*)alloc((size_t)B * DV * 2);
    short* ctx_b  = (short*)alloc((size_t)B * DV * 2);
    short* hc_b   = (short*)alloc((size_t)B * 2048 * 2);         // [128][2048]: h0 | c0
    short* emb_b  = (short*)alloc((size_t)TT * B * EMB * 2);
    short* words_bf = (short*)alloc((size_t)TT * B * VV * 2);    // 51.2 MB

    // ---- merged weight conversion (one launch) ----
    {
        size_t total = N_WOUT + N_WIH + N_WHH + 2 * N_WINI;
        convert_all_kernel<<<(total + 255) / 256, 256, 0, stream>>>(
            W_out, Wout_b, W_ih, Wih_b, W_hh, Whh_b,
            W_init_h, Wini_h_b, W_init_c, Wini_c_b);
    }

    // ---- phase 1: time-parallel ----
    attv_kernel<<<B * NLOC, 64, 0, stream>>>(features, W_attn_v, b_attn_v, attv);
    alpha_kernel<<<B, 256, 0, stream>>>(attv, alpha);
    fmeanctx_kernel<<<(B * DV + 255) / 256, 256, 0, stream>>>(features, alpha, fmean_b, ctx_b);
    emb_gather_kernel<<<((size_t)TT * B * EMB / 4 + 255) / 256, 256, 0, stream>>>(
        captions, embed_table, emb_b);

    // fused h0|c0 GEMM: [128][2048] = fmean @ [Wini_h; Wini_c]^T; c-half also
    // stored fp32 straight into cbuf via the Caux epilogue
    gemm_bf16<32, 4, 1, true><<<dim3(2048 / 32), 256, 0, stream>>>(
        fmean_b, Wini_h_b, hc_b, cbuf, nullptr, nullptr, 1, B, 2048, DV, DV, DV, 2048);

    // gctx (bf16 out, BK=32 proven)
    gemm_bf16<32, 4, 1, true><<<dim3(G4 / 32), 256, 0, stream>>>(
        ctx_b, Wih_b, gctx_b, nullptr, b_ih, b_hh, 1, B, G4, DV, DV, HD, G4);
    // gate_pre (bf16 out, BK=64, XCD swizzle; gctx folded in via addrow epilogue)
    gemm_k64<<<dim3((G4 / 128) * (TT * B / 128)), 256, 0, stream>>>(
        emb_b, Wih_b + DV, gate_pre_b, nullptr, gctx_b, TT * B / 128,
        TT * B, G4, EMB, EMB, DV + EMB, G4);

    // ---- phase 2: fused recurrence (v9b, round-20/22 proven) ----
    for (int t = 0; t < TT; ++t) {
        const short* Hprev = (t == 0) ? hc_b : (Hall_b + (size_t)(t - 1) * BH);
        int lda = (t == 0) ? 2048 : HD;
        lstm_step9<<<dim3(G4 / 32, B / 32), 256, 0, stream>>>(
            Hprev, lda, Whh_b, gate_pre_b + (size_t)t * B * G4,
            cbuf, Hall_b + (size_t)t * BH);
    }

    // ---- phase 3: words (bf16) = Hall @ W_out^T + b_out (BK=64, XCD swizzle) ----
    gemm_k64<<<dim3((VPAD / 128) * (TT * B / 128)), 256, 0, stream>>>(
        Hall_b, Wout_b, words_bf, b_out, nullptr, TT * B / 128,
        TT * B, VV, HD, HD, HD, VV);
    softmax_kernel<<<TT * B, 512, 0, stream>>>(words_bf, words, s2);
}

// Round 25
// 425.129 us; speedup vs baseline: 1.1054x; 1.0116x over previous
//
#include <hip/hip_runtime.h>
#include <math.h>

#define B    128
#define NLOC 196
#define DV   512
#define EMB  512
#define HD   1024
#define VV   10000
#define TT   20
#define G4   4096   // 4*HD
#define VPAD 10112  // 79*128
#define BH   (B*HD)

typedef short bf16x8 __attribute__((ext_vector_type(8)));
typedef short s16x4  __attribute__((ext_vector_type(4)));
typedef float f32x4  __attribute__((ext_vector_type(4)));

__device__ __forceinline__ unsigned short f2bf(float x) {
    unsigned u = __builtin_bit_cast(unsigned, x);
    unsigned r = (u + 0x7fffu + ((u >> 16) & 1u)) >> 16;
    return (unsigned short)r;
}
__device__ __forceinline__ float bf2f(short s) {
    unsigned u = ((unsigned)(unsigned short)s) << 16;
    return __builtin_bit_cast(float, u);
}

__device__ __forceinline__ void gload_lds16(const void* g, void* lds) {
    __builtin_amdgcn_global_load_lds(
        (const __attribute__((address_space(1))) void*)g,
        (__attribute__((address_space(3))) void*)lds, 16, 0, 0);
}

// ---------------- small kernels ----------------

__global__ void attv_kernel(const float* __restrict__ feat, const float* __restrict__ wv,
                            const float* __restrict__ bv, float* __restrict__ attv) {
    int row  = blockIdx.x;         // B*NLOC
    int lane = threadIdx.x;        // 64
    const float* p = feat + (size_t)row * DV;
    float s = 0.f;
    for (int k = lane; k < DV; k += 64) s += p[k] * wv[k];
    for (int off = 32; off > 0; off >>= 1) s += __shfl_down(s, off);
    if (lane == 0) attv[row] = s + bv[0];
}

__global__ void alpha_kernel(const float* __restrict__ attv, float* __restrict__ alpha) {
    int b   = blockIdx.x;          // B
    int tid = threadIdx.x;         // 256
    __shared__ float red[256];
    float v = (tid < NLOC) ? attv[b * NLOC + tid] : -1e30f;
    red[tid] = v; __syncthreads();
    for (int s = 128; s > 0; s >>= 1) { if (tid < s) red[tid] = fmaxf(red[tid], red[tid + s]); __syncthreads(); }
    float m = red[0]; __syncthreads();
    float e = (tid < NLOC) ? expf(v - m) : 0.f;
    red[tid] = e; __syncthreads();
    for (int s = 128; s > 0; s >>= 1) { if (tid < s) red[tid] += red[tid + s]; __syncthreads(); }
    float sum = red[0];
    if (tid < NLOC) alpha[b * NLOC + tid] = e / sum;
}

// fused: fmean (mean over n) + ctx (alpha-weighted sum over n) in ONE feature pass
__global__ void fmeanctx_kernel(const float* __restrict__ feat, const float* __restrict__ alpha,
                                short* __restrict__ fmean_b, short* __restrict__ ctx_b) {
    int idx = blockIdx.x * blockDim.x + threadIdx.x;   // B*DV
    if (idx >= B * DV) return;
    int b = idx / DV, d = idx % DV;
    const float* p = feat + (size_t)b * NLOC * DV + d;
    const float* a = alpha + b * NLOC;
    float sm = 0.f, sc = 0.f;
    for (int n = 0; n < NLOC; ++n) {
        float v = p[(size_t)n * DV];
        sm += v;
        sc += a[n] * v;
    }
    fmean_b[idx] = (short)f2bf(sm * (1.0f / NLOC));
    ctx_b[idx]   = (short)f2bf(sc);
}

// vectorized gather: 4 consecutive emb elems per thread
__global__ void emb_gather_kernel(const int* __restrict__ captions, const float* __restrict__ table,
                                  short* __restrict__ emb_b) {
    size_t q = (size_t)blockIdx.x * blockDim.x + threadIdx.x;   // T*B*EMB/4
    if (q >= (size_t)TT * B * EMB / 4) return;
    size_t idx = q * 4;
    int k = (int)(idx % EMB);
    int r = (int)(idx / EMB);      // r = t*B + b
    int t = r / B, b = r % B;
    int cap = captions[b * TT + t];
    float4 v = *(const float4*)&table[(size_t)cap * EMB + k];
    s16x4 o = { (short)f2bf(v.x), (short)f2bf(v.y), (short)f2bf(v.z), (short)f2bf(v.w) };
    *(s16x4*)&emb_b[idx] = o;
}

// ONE merged conversion kernel: ranges [Wout | Wih | Whh(permuted) | Wini_h | Wini_c]
#define N_WOUT ((size_t)VPAD * HD / 4)
#define N_WIH  ((size_t)G4 * HD / 4)
#define N_WHH  ((size_t)G4 * HD / 4)
#define N_WINI ((size_t)HD * DV / 4)
__global__ void convert_all_kernel(const float* __restrict__ W_out, short* __restrict__ Wout_b,
                                   const float* __restrict__ W_ih,  short* __restrict__ Wih_b,
                                   const float* __restrict__ W_hh,  short* __restrict__ Whh_b,
                                   const float* __restrict__ W_ini_h, short* __restrict__ Wini_h_b,
                                   const float* __restrict__ W_ini_c, short* __restrict__ Wini_c_b) {
    size_t q = (size_t)blockIdx.x * blockDim.x + threadIdx.x;
    size_t idx;
    if (q < N_WOUT) {
        idx = q * 4;
        size_t n = (size_t)VV * HD;
        s16x4 o = {0, 0, 0, 0};
        if (idx < n) {
            float4 v = *(const float4*)&W_out[idx];
            o = s16x4{ (short)f2bf(v.x), (short)f2bf(v.y), (short)f2bf(v.z), (short)f2bf(v.w) };
        }
        *(s16x4*)&Wout_b[idx] = o;
        return;
    }
    q -= N_WOUT;
    if (q < N_WIH) {
        idx = q * 4;
        float4 v = *(const float4*)&W_ih[idx];
        s16x4 o = { (short)f2bf(v.x), (short)f2bf(v.y), (short)f2bf(v.z), (short)f2bf(v.w) };
        *(s16x4*)&Wih_b[idx] = o;
        return;
    }
    q -= N_WIH;
    if (q < N_WHH) {
        idx = q * 4;
        int k = (int)(idx & (HD - 1));
        int P = (int)(idx >> 10);
        int u = P >> 2, g = P & 3;
        float4 v = *(const float4*)&W_hh[(size_t)(g * HD + u) * HD + k];
        s16x4 o = { (short)f2bf(v.x), (short)f2bf(v.y), (short)f2bf(v.z), (short)f2bf(v.w) };
        *(s16x4*)&Whh_b[idx] = o;
        return;
    }
    q -= N_WHH;
    if (q < N_WINI) {
        idx = q * 4;
        float4 v = *(const float4*)&W_ini_h[idx];
        s16x4 o = { (short)f2bf(v.x), (short)f2bf(v.y), (short)f2bf(v.z), (short)f2bf(v.w) };
        *(s16x4*)&Wini_h_b[idx] = o;
        return;
    }
    q -= N_WINI;
    if (q < N_WINI) {
        idx = q * 4;
        float4 v = *(const float4*)&W_ini_c[idx];
        s16x4 o = { (short)f2bf(v.x), (short)f2bf(v.y), (short)f2bf(v.z), (short)f2bf(v.w) };
        *(s16x4*)&Wini_c_b[idx] = o;
    }
}

// ---------------- bf16 MFMA GEMM BK=32 (proven) + optional fp32 aux store for col>=1024 ----------------
template<int BN, int WR, int WC, bool BF16OUT>
__global__ __launch_bounds__(256)
void gemm_bf16(const short* __restrict__ A, const short* __restrict__ Bw,
               void* __restrict__ C, float* __restrict__ Caux,
               const float* __restrict__ bias0, const float* __restrict__ bias1,
               int NY, int M, int N, int K, int lda, int ldb, int ldc) {
    constexpr int BM = 128;
    constexpr int BK = 32;
    constexpr int WM = BM / WR;
    constexpr int WN = BN / WC;
    constexpr int FM = WM / 16;
    constexpr int FN = WN / 16;
    __shared__ __align__(16) short As[BM * BK];
    __shared__ __align__(16) short Bs[BN * BK];
    const int tid  = threadIdx.x;
    const int wave = tid >> 6, lane = tid & 63;
    const int wr = wave / WC, wc = wave % WC;

    const int nwg = gridDim.x;
    const int qq = nwg >> 3, rr8 = nwg & 7;
    const int p = blockIdx.x;
    const int xcd = p & 7, slot = p >> 3;
    const int lwg = (xcd < rr8) ? (xcd * (qq + 1) + slot)
                                : (rr8 * (qq + 1) + (xcd - rr8) * qq + slot);
    const int m0 = (lwg % NY) * BM;
    const int n0 = (lwg / NY) * BN;
    const int laneoff = lane * 16;

    f32x4 acc[FM][FN] = {};

    for (int k0 = 0; k0 < K; k0 += BK) {
        #pragma unroll
        for (int r = 0; r < 2; ++r) {
            int o   = r * 4096 + wave * 1024 + laneoff;
            int row = o >> 6;
            int gr  = (o >> 4) & 3;
            int col = ((gr ^ ((row >> 1) & 3)) << 3);
            gload_lds16(A + (size_t)(m0 + row) * lda + k0 + col,
                        (char*)As + r * 4096 + wave * 1024);
        }
        constexpr int BBYTES = BN * BK * 2;
        if constexpr (BBYTES >= 4096) {
            #pragma unroll
            for (int r = 0; r < BBYTES / 4096; ++r) {
                int o   = r * 4096 + wave * 1024 + laneoff;
                int row = o >> 6;
                int gr  = (o >> 4) & 3;
                int col = ((gr ^ ((row >> 1) & 3)) << 3);
                gload_lds16(Bw + (size_t)(n0 + row) * ldb + k0 + col,
                            (char*)Bs + r * 4096 + wave * 1024);
            }
        } else {
            constexpr int NW = BBYTES / 1024;
            if (wave < NW) {
                int o   = wave * 1024 + laneoff;
                int row = o >> 6;
                int gr  = (o >> 4) & 3;
                int col = ((gr ^ ((row >> 1) & 3)) << 3);
                gload_lds16(Bw + (size_t)(n0 + row) * ldb + k0 + col,
                            (char*)Bs + wave * 1024);
            }
        }
        __syncthreads();

        bf16x8 a[FM], b[FN];
        const int kfrg = lane >> 4;
        #pragma unroll
        for (int i = 0; i < FM; ++i) {
            int row = wr * WM + i * 16 + (lane & 15);
            a[i] = *(const bf16x8*)&As[row * BK + ((kfrg ^ ((row >> 1) & 3)) << 3)];
        }
        #pragma unroll
        for (int j = 0; j < FN; ++j) {
            int row = wc * WN + j * 16 + (lane & 15);
            b[j] = *(const bf16x8*)&Bs[row * BK + ((kfrg ^ ((row >> 1) & 3)) << 3)];
        }
        #pragma unroll
        for (int i = 0; i < FM; ++i)
            #pragma unroll
            for (int j = 0; j < FN; ++j)
                acc[i][j] = __builtin_amdgcn_mfma_f32_16x16x32_bf16(a[i], b[j], acc[i][j], 0, 0, 0);
        __syncthreads();
    }

    #pragma unroll
    for (int i = 0; i < FM; ++i) {
        #pragma unroll
        for (int j = 0; j < FN; ++j) {
            int col = n0 + wc * WN + j * 16 + (lane & 15);
            if (col >= N) continue;
            float bv = (bias0 ? bias0[col] : 0.f) + (bias1 ? bias1[col] : 0.f);
            #pragma unroll
            for (int q = 0; q < 4; ++q) {
                int row = m0 + wr * WM + i * 16 + (lane >> 4) * 4 + q;
                if (row < M) {
                    float v = acc[i][j][q] + bv;
                    if constexpr (BF16OUT)
                        ((short*)C)[(size_t)row * ldc + col] = (short)f2bf(v);
                    else
                        ((float*)C)[(size_t)row * ldc + col] = v;
                    if (Caux && col >= 1024)
                        Caux[(size_t)row * 1024 + (col - 1024)] = v;
                }
            }
        }
    }
}

// ---------------- bf16 MFMA GEMM BK=64 (proven) + optional per-(row%128,col) add ----------------
__global__ __launch_bounds__(256)
void gemm_k64(const short* __restrict__ A, const short* __restrict__ Bw,
              short* __restrict__ C,
              const float* __restrict__ bias0, const short* __restrict__ addrow,
              int NY, int M, int N, int K, int lda, int ldb, int ldc) {
    __shared__ __align__(16) short As[128 * 64];   // 16 KB
    __shared__ __align__(16) short Bs[128 * 64];   // 16 KB
    const int tid  = threadIdx.x;
    const int wave = tid >> 6, lane = tid & 63;
    const int wr = wave >> 1, wc = wave & 1;

    const int nwg = gridDim.x;
    const int qq = nwg >> 3, rr8 = nwg & 7;
    const int p = blockIdx.x;
    const int xcd = p & 7, slot = p >> 3;
    const int lwg = (xcd < rr8) ? (xcd * (qq + 1) + slot)
                                : (rr8 * (qq + 1) + (xcd - rr8) * qq + slot);
    const int m0 = (lwg % NY) * 128;
    const int n0 = (lwg / NY) * 128;
    const int laneoff = lane * 16;
    const int kfrg = lane >> 4;

    f32x4 acc[4][4] = {};

    for (int k0 = 0; k0 < K; k0 += 64) {
        #pragma unroll
        for (int r = 0; r < 4; ++r) {
            int o   = r * 4096 + wave * 1024 + laneoff;
            int row = o >> 7;                            // 128 B per row
            int gr  = (o >> 4) & 7;
            int col = ((gr ^ (row & 7)) << 3);
            gload_lds16(A + (size_t)(m0 + row) * lda + k0 + col,
                        (char*)As + r * 4096 + wave * 1024);
            gload_lds16(Bw + (size_t)(n0 + row) * ldb + k0 + col,
                        (char*)Bs + r * 4096 + wave * 1024);
        }
        __syncthreads();

        #pragma unroll
        for (int kh = 0; kh < 2; ++kh) {
            bf16x8 a[4], b[4];
            #pragma unroll
            for (int i = 0; i < 4; ++i) {
                int row = wr * 64 + i * 16 + (lane & 15);
                a[i] = *(const bf16x8*)&As[row * 64 + (((kh * 4 + kfrg) ^ (row & 7)) << 3)];
            }
            #pragma unroll
            for (int j = 0; j < 4; ++j) {
                int row = wc * 64 + j * 16 + (lane & 15);
                b[j] = *(const bf16x8*)&Bs[row * 64 + (((kh * 4 + kfrg) ^ (row & 7)) << 3)];
            }
            #pragma unroll
            for (int i = 0; i < 4; ++i)
                #pragma unroll
                for (int j = 0; j < 4; ++j)
                    acc[i][j] = __builtin_amdgcn_mfma_f32_16x16x32_bf16(a[i], b[j], acc[i][j], 0, 0, 0);
        }
        __syncthreads();
    }

    #pragma unroll
    for (int i = 0; i < 4; ++i) {
        #pragma unroll
        for (int j = 0; j < 4; ++j) {
            int col = n0 + wc * 64 + j * 16 + (lane & 15);
            if (col >= N) continue;
            float bv = bias0 ? bias0[col] : 0.f;
            #pragma unroll
            for (int q = 0; q < 4; ++q) {
                int row = m0 + wr * 64 + i * 16 + (lane >> 4) * 4 + q;
                if (row < M) {
                    float v = acc[i][j][q] + bv;
                    if (addrow) v += bf2f(addrow[(size_t)(row & 127) * ldc + col]);
                    C[(size_t)row * ldc + col] = (short)f2bf(v);
                }
            }
        }
    }
}

// ---------------- fused recurrence step v9b (round-20/22 proven): gctx pre-folded ----------------
__global__ __launch_bounds__(256)
void lstm_step9(const short* __restrict__ Hprev, int lda, const short* __restrict__ Whh_p,
                const short* __restrict__ pre_t,
                float* __restrict__ cbuf, short* __restrict__ Hall_t) {
    __shared__ __align__(16) short As[32 * 512];    // 32 KB (half-K)
    __shared__ __align__(16) short Ws[32 * 512];    // 32 KB
    __shared__ float gsm[4][32][8];                 // 4 KB
    const int tid  = threadIdx.x;
    const int lane = tid & 63, wave = tid >> 6;
    const int n0 = blockIdx.x * 32;                 // P base (units blockIdx.x*8..+7)
    const int m0 = blockIdx.y * 32;                 // batch base

    const int mi = wave >> 1, ni = wave & 1;        // wave's 16x16 tile of the 32x32
    const int arowL = mi * 16 + (lane & 15);
    const int browL = ni * 16 + (lane & 15);
    const int kg    = lane >> 4;

    f32x4 acc = {};

    for (int h2 = 0; h2 < 2; ++h2) {
        const int k0 = h2 * 512;
        #pragma unroll
        for (int it = 0; it < 8; ++it) {
            int fg  = it * 256 + tid;
            int row = fg >> 6;                      // 64 granules (1024 B) per row
            int g   = fg & 63;
            int col = (g ^ (row & 7)) * 8;          // pre-swizzled global elem col
            gload_lds16(Hprev + (size_t)(m0 + row) * lda + k0 + col,
                        (char*)As + it * 4096 + wave * 1024);
            gload_lds16(Whh_p + (size_t)(n0 + row) * HD + k0 + col,
                        (char*)Ws + it * 4096 + wave * 1024);
        }
        __syncthreads();
        #pragma unroll
        for (int ks = 0; ks < 16; ++ks) {
            int lg = ks * 4 + kg;                   // logical granule 0..63
            bf16x8 a = *(const bf16x8*)((const char*)As + arowL * 1024 + ((lg ^ (arowL & 7)) << 4));
            bf16x8 w = *(const bf16x8*)((const char*)Ws + browL * 1024 + ((lg ^ (browL & 7)) << 4));
            acc = __builtin_amdgcn_mfma_f32_16x16x32_bf16(a, w, acc, 0, 0, 0);
        }
        __syncthreads();                            // reads done before restage
    }

    // scatter gates: wave tile (mi, ni); lane col p = browL -> unit p>>2, gate p&3
    #pragma unroll
    for (int q = 0; q < 4; ++q) {
        int rr = mi * 16 + (lane >> 4) * 4 + q;
        gsm[browL & 3][rr][browL >> 2] = acc[q];
    }
    __syncthreads();

    // fused LSTM elementwise: pre_t already contains gctx + biases
    const int m = tid >> 3, u8 = tid & 7;
    const int r = m0 + m, u = blockIdx.x * 8 + u8;
    size_t pb = (size_t)r * G4 + u;
    float gi  = gsm[0][m][u8] + bf2f(pre_t[pb]);
    float gf  = gsm[1][m][u8] + bf2f(pre_t[pb + HD]);
    float gg2 = gsm[2][m][u8] + bf2f(pre_t[pb + 2 * HD]);
    float go  = gsm[3][m][u8] + bf2f(pre_t[pb + 3 * HD]);
    float si = 1.f / (1.f + expf(-gi));
    float sf = 1.f / (1.f + expf(-gf));
    float so = 1.f / (1.f + expf(-go));
    float cn = sf * cbuf[(size_t)r * HD + u] + si * tanhf(gg2);
    float hn = so * tanhf(cn);
    cbuf[(size_t)r * HD + u] = cn;
    Hall_t[(size_t)r * HD + u] = (short)f2bf(hn);
}

// ---------------- single-pass LDS softmax: bf16 logits in, two fp32 outputs ----------------
__global__ __launch_bounds__(512)
void softmax_kernel(const short* __restrict__ wbf, float* __restrict__ logout,
                    float* __restrict__ smout) {
    __shared__ float rowbuf[VV];   // 40 KB
    __shared__ float red[512];
    int r = blockIdx.x;            // T*B rows
    int tid = threadIdx.x;         // 512
    const short* row = wbf + (size_t)r * VV;
    float m = -1e30f;
    for (int i = tid; i < VV; i += 512) {
        float v = bf2f(row[i]);
        rowbuf[i] = v;
        m = fmaxf(m, v);
    }
    red[tid] = m; __syncthreads();
    for (int s = 256; s > 0; s >>= 1) { if (tid < s) red[tid] = fmaxf(red[tid], red[tid + s]); __syncthreads(); }
    m = red[0]; __syncthreads();
    float sum = 0.f;
    for (int i = tid; i < VV; i += 512) sum += expf(rowbuf[i] - m);
    red[tid] = sum; __syncthreads();
    for (int s = 256; s > 0; s >>= 1) { if (tid < s) red[tid] += red[tid + s]; __syncthreads(); }
    sum = red[0];
    float inv = 1.f / sum;
    float lz = logf(sum);
    for (int i = tid; i < VV; i += 512) {
        float x = rowbuf[i];
        smout[(size_t)r * VV + i]  = expf(x - m) * inv;
        logout[(size_t)r * VV + i] = x - m - lz;
    }
}

// ---------------- launch ----------------
extern "C" void kernel_launch(void* const* d_in, const int* in_sizes, int n_in,
                              void* d_out, int out_size, void* d_ws, size_t ws_size,
                              hipStream_t stream) {
    const float* features    = (const float*)d_in[0];
    const int*   captions    = (const int*)  d_in[1];
    const float* W_init_h    = (const float*)d_in[2];
    const float* W_init_c    = (const float*)d_in[3];
    const float* W_attn_v    = (const float*)d_in[4];
    const float* b_attn_v    = (const float*)d_in[5];
    // d_in[6], d_in[7] (W_attn_h, b_attn_h) dead: softmax shift-invariance.
    const float* embed_table = (const float*)d_in[8];
    const float* W_ih        = (const float*)d_in[9];
    const float* W_hh        = (const float*)d_in[10];
    const float* b_ih        = (const float*)d_in[11];
    const float* b_hh        = (const float*)d_in[12];
    const float* W_out       = (const float*)d_in[13];
    const float* b_out       = (const float*)d_in[14];

    float* out   = (float*)d_out;
    float* words = out;                        // first half: final log_softmax
    float* s2    = out + (size_t)TT * B * VV;  // second half: scratch, then softmax out

    // second-half scratch — slot offsets FROZEN
    short* gate_pre_b = (short*)s2;                              // bf16 in frozen slot
    short* Hall_b   = (short*)(s2 + (size_t)10485760);           // TT x B*HD bf16
    short* Wout_b   = (short*)(s2 + (size_t)10485760 + 1310720); // VPAD*HD
    short* Wih_b    = Wout_b + (size_t)VPAD * HD;
    short* Whh_b    = Wih_b  + (size_t)G4 * HD;                  // PERMUTED W_hh
    short* Wini_h_b = Whh_b  + (size_t)G4 * HD;                  // [1024][512]
    short* Wini_c_b = Wini_h_b + (size_t)HD * DV;                // [1024][512] (contiguous)

    // ws small scratch (+ bf16 words buffer)
    char* w = (char*)d_ws;
    size_t off = 0;
    auto alloc = [&](size_t bytes) { void* p = w + off; off = (off + bytes + 255) & ~255UL; return p; };
    float* attv   = (float*)alloc((size_t)B * NLOC * 4);
    float* alpha  = (float*)alloc((size_t)B * NLOC * 4);
    short* gctx_b = (short*)alloc((size_t)B * G4 * 2);
    float* cbuf   = (float*)alloc((size_t)B * HD * 4);
    short* fmean_b= (short*)alloc((size_t)B * DV * 2);
    short* ctx_b  = (short*)alloc((size_t)B * DV * 2);
    short* hc_b   = (short*)alloc((size_t)B * 2048 * 2);         // [128][2048]: h0 | c0
    short* emb_b  = (short*)alloc((size_t)TT * B * EMB * 2);
    short* words_bf = (short*)alloc((size_t)TT * B * VV * 2);    // 51.2 MB

    // ---- merged weight conversion (one launch) ----
    {
        size_t total = N_WOUT + N_WIH + N_WHH + 2 * N_WINI;
        convert_all_kernel<<<(total + 255) / 256, 256, 0, stream>>>(
            W_out, Wout_b, W_ih, Wih_b, W_hh, Whh_b,
            W_init_h, Wini_h_b, W_init_c, Wini_c_b);
    }

    // ---- phase 1: time-parallel ----
    attv_kernel<<<B * NLOC, 64, 0, stream>>>(features, W_attn_v, b_attn_v, attv);
    alpha_kernel<<<B, 256, 0, stream>>>(attv, alpha);
    fmeanctx_kernel<<<(B * DV + 255) / 256, 256, 0, stream>>>(features, alpha, fmean_b, ctx_b);
    emb_gather_kernel<<<((size_t)TT * B * EMB / 4 + 255) / 256, 256, 0, stream>>>(
        captions, embed_table, emb_b);

    // fused h0|c0 GEMM: [128][2048] = fmean @ [Wini_h; Wini_c]^T; c-half also
    // stored fp32 straight into cbuf via the Caux epilogue
    gemm_bf16<32, 4, 1, true><<<dim3(2048 / 32), 256, 0, stream>>>(
        fmean_b, Wini_h_b, hc_b, cbuf, nullptr, nullptr, 1, B, 2048, DV, DV, DV, 2048);

    // gctx (bf16 out, BK=32 proven)
    gemm_bf16<32, 4, 1, true><<<dim3(G4 / 32), 256, 0, stream>>>(
        ctx_b, Wih_b, gctx_b, nullptr, b_ih, b_hh, 1, B, G4, DV, DV, HD, G4);
    // gate_pre (bf16 out, BK=64, XCD swizzle; gctx folded in via addrow epilogue)
    gemm_k64<<<dim3((G4 / 128) * (TT * B / 128)), 256, 0, stream>>>(
        emb_b, Wih_b + DV, gate_pre_b, nullptr, gctx_b, TT * B / 128,
        TT * B, G4, EMB, EMB, DV + EMB, G4);

    // ---- phase 2: fused recurrence (v9b, round-20/22 proven) ----
    for (int t = 0; t < TT; ++t) {
        const short* Hprev = (t == 0) ? hc_b : (Hall_b + (size_t)(t - 1) * BH);
        int lda = (t == 0) ? 2048 : HD;
        lstm_step9<<<dim3(G4 / 32, B / 32), 256, 0, stream>>>(
            Hprev, lda, Whh_b, gate_pre_b + (size_t)t * B * G4,
            cbuf, Hall_b + (size_t)t * BH);
    }

    // ---- phase 3: words (bf16) = Hall @ W_out^T + b_out (BK=64, XCD swizzle) ----
    gemm_k64<<<dim3((VPAD / 128) * (TT * B / 128)), 256, 0, stream>>>(
        Hall_b, Wout_b, words_bf, b_out, nullptr, TT * B / 128,
        TT * B, VV, HD, HD, HD, VV);
    softmax_kernel<<<TT * B, 512, 0, stream>>>(words_bf, words, s2);
}